// Round 1
// baseline (530.431 us; speedup 1.0000x reference)
//
#include <hip/hip_runtime.h>
#include <hip/hip_bf16.h>

// B=2, N=4096 (64x64), DIM=128, NH=4, dh=32
// d_out = out[2,4096,128] fp32 (1048576) ++ attn[2,4,4096,4096] fp32 (134217728)
// rel_index input is IGNORED: idx = (rn-rm+63)*127 + (cn-cm+63), rn=n>>6, cn=n&63.

typedef short s16x8 __attribute__((ext_vector_type(8)));
typedef float f32x4 __attribute__((ext_vector_type(4)));

#define LOG2E 1.4426950408889634f

__device__ __forceinline__ float bf2f(short u) {
  union { unsigned int i; float f; } v;
  v.i = ((unsigned int)(unsigned short)u) << 16;
  return v.f;
}
__device__ __forceinline__ short f2bf(float f) {
  union { float f; unsigned int i; } v; v.f = f;
  unsigned int r = v.i + 0x7FFFu + ((v.i >> 16) & 1u);  // RNE
  return (short)(r >> 16);
}

// ---------------- Kernel 1: QKV projections (fp32 -> bf16) ----------------
// q16/k16: [bh=8][n=4096][d=32]   vT16: [bh=8][d=32][n=4096]
__global__ __launch_bounds__(256)
void qkv_kernel(const float* __restrict__ x,
                const float* __restrict__ q_w, const float* __restrict__ q_b,
                const float* __restrict__ kv_w, const float* __restrict__ kv_b,
                short* __restrict__ q16, short* __restrict__ k16, short* __restrict__ vT16)
{
  __shared__ float xs[16][129];   // stride 129 -> conflict-free column reads
  const int tid = threadIdx.x;
  const int row0 = blockIdx.x * 16;          // flat row in [0, 8192)
  for (int i = tid; i < 16*128; i += 256) {
    int r = i >> 7, c = i & 127;
    xs[r][c] = x[(size_t)(row0 + r)*128 + c];
  }
  __syncthreads();

  // q/k outputs, oc in [0,256), oc-fastest lanes for coalesced-ish 2B stores
  for (int it = 0; it < 16; ++it) {
    int oc = ((it & 1) << 7) + (tid & 127);   // 0..255
    int r  = ((it >> 1) << 1) + (tid >> 7);   // 0..15
    const float* wrow = (oc < 128) ? (q_w + (size_t)oc*128) : (kv_w + (size_t)(oc-128)*128);
    float acc = (oc < 128) ? q_b[oc] : kv_b[oc-128];
    const float4* w4 = (const float4*)wrow;
    #pragma unroll 8
    for (int k4 = 0; k4 < 32; ++k4) {
      float4 wv = w4[k4];
      int k = k4 << 2;
      acc = fmaf(xs[r][k  ], wv.x, acc);
      acc = fmaf(xs[r][k+1], wv.y, acc);
      acc = fmaf(xs[r][k+2], wv.z, acc);
      acc = fmaf(xs[r][k+3], wv.w, acc);
    }
    int n = row0 + r;
    int b = n >> 12, nn = n & 4095;
    short val = f2bf(acc);
    if (oc < 128) {
      int hh = oc >> 5, d = oc & 31;
      q16[((size_t)((b<<2) + hh)*4096 + nn)*32 + d] = val;
    } else {
      int j = oc - 128, hh = j >> 5, d = j & 31;
      k16[((size_t)((b<<2) + hh)*4096 + nn)*32 + d] = val;
    }
  }
  // v outputs, n-fastest lanes for coalesced vT stores
  for (int it = 0; it < 8; ++it) {
    int idx2 = (it << 8) + tid;
    int r  = idx2 & 15;
    int vd = idx2 >> 4;                       // 0..127
    const float* wrow = kv_w + (size_t)(128 + vd)*128;
    float acc = kv_b[128 + vd];
    const float4* w4 = (const float4*)wrow;
    #pragma unroll 8
    for (int k4 = 0; k4 < 32; ++k4) {
      float4 wv = w4[k4];
      int k = k4 << 2;
      acc = fmaf(xs[r][k  ], wv.x, acc);
      acc = fmaf(xs[r][k+1], wv.y, acc);
      acc = fmaf(xs[r][k+2], wv.z, acc);
      acc = fmaf(xs[r][k+3], wv.w, acc);
    }
    int n = row0 + r;
    int b = n >> 12, nn = n & 4095;
    int hh = vd >> 5, d = vd & 31;
    vT16[((size_t)((b<<2) + hh)*32 + d)*4096 + nn] = f2bf(acc);
  }
}

// ---------------- Kernel 2: fused attention ----------------
// One block = 16 query rows, loops over all 8 (b,h). P tile 16x4096 bf16 in LDS,
// XOR-swizzled (byte ^= (row&7)<<4) for conflict-free ds_read_b128 / stores.
__global__ __launch_bounds__(512)
void attn_kernel(const short* __restrict__ q16, const short* __restrict__ k16,
                 const short* __restrict__ vT16, const float* __restrict__ bias_table,
                 float* __restrict__ attn_out, float* __restrict__ out_stage)
{
  __shared__ __align__(16) char Plds[16 * 8192];   // 128 KB
  __shared__ float wm[16*8];
  __shared__ float mrow[16];
  __shared__ float srow[16];
  __shared__ float pvp[8*16*32];                   // 16 KB

  const int tid  = threadIdx.x;
  const int wave = tid >> 6;
  const int lane = tid & 63;
  const int l15  = lane & 15;
  const int lg   = lane >> 4;        // 0..3
  const int row0 = blockIdx.x * 16;
  const float scale = 0.17677669529663687f;  // 32^-0.5

  // per-row analytic rel-index term: idx = rt[j] - (rm*127 + cm)
  int rt[4];
  #pragma unroll
  for (int j = 0; j < 4; ++j) {
    int gr = row0 + lg*4 + j;
    rt[j] = (gr >> 6)*127 + (gr & 63) + 8064;   // 63*127 + 63 = 8064
  }

  for (int bh = 0; bh < 8; ++bh) {
    const int h = bh & 3;
    const size_t base = (size_t)bh * (4096*32);

    // Q fragment: A[r=l15][k=lg*8+i], contiguous 16B
    s16x8 afrag = *(const s16x8*)(q16 + base + (size_t)(row0 + l15)*32 + lg*8);

    float runmax[4] = {-1e30f, -1e30f, -1e30f, -1e30f};

    // ---- QK^T sweep: wave w handles col-tiles ct = w + 8*i ----
    for (int i = 0; i < 32; ++i) {
      int ct = wave + (i << 3);
      int mm = (ct << 4) + l15;                 // global col for this lane
      s16x8 bfrag = *(const s16x8*)(k16 + base + (size_t)mm*32 + lg*8);
      f32x4 z = {0.f, 0.f, 0.f, 0.f};
      f32x4 d = __builtin_amdgcn_mfma_f32_16x16x32_bf16(afrag, bfrag, z, 0, 0, 0);
      int mterm = (mm >> 6)*127 + (mm & 63);
      #pragma unroll
      for (int j = 0; j < 4; ++j) {
        int r = lg*4 + j;                        // D row
        int idx = rt[j] - mterm;
        float L = fmaf(d[j], scale, bias_table[(idx << 2) + h]);
        runmax[j] = fmaxf(runmax[j], L);
        int off = ((r << 13) + (mm << 1)) ^ ((r & 7) << 4);
        *(short*)(Plds + off) = f2bf(L);
      }
    }
    // per-wave per-row max (reduce over the 16 lanes sharing a row)
    #pragma unroll
    for (int j = 0; j < 4; ++j) {
      float v = runmax[j];
      v = fmaxf(v, __shfl_xor(v, 1));
      v = fmaxf(v, __shfl_xor(v, 2));
      v = fmaxf(v, __shfl_xor(v, 4));
      v = fmaxf(v, __shfl_xor(v, 8));
      if (l15 == 0) wm[(lg*4 + j)*8 + wave] = v;
    }
    __syncthreads();
    if (tid < 16) {
      float v = wm[tid*8];
      #pragma unroll
      for (int w = 1; w < 8; ++w) v = fmaxf(v, wm[tid*8 + w]);
      mrow[tid] = v;
    }
    __syncthreads();

    // ---- exp sweep: row r = tid>>5, 32 threads/row, 16B LDS units ----
    {
      const int r = tid >> 5;
      const int c32 = tid & 31;
      const float mx = mrow[r];
      float s = 0.f;
      for (int iu = 0; iu < 16; ++iu) {
        int u = c32 + (iu << 5);
        int off = ((r << 13) + (u << 4)) ^ ((r & 7) << 4);
        s16x8* p = (s16x8*)(Plds + off);
        s16x8 pv = *p;
        s16x8 ev;
        #pragma unroll
        for (int e = 0; e < 8; ++e) {
          float L = bf2f(pv[e]);
          float xv = __builtin_amdgcn_exp2f((L - mx) * LOG2E);
          s += xv;
          ev[e] = f2bf(xv);
        }
        *p = ev;
      }
      #pragma unroll
      for (int msk = 1; msk < 32; msk <<= 1) s += __shfl_xor(s, msk);
      if (c32 == 0) srow[r] = s;
    }
    __syncthreads();

    // ---- attn write (fire-and-forget) then PV MFMA ----
    {
      const int r = tid >> 5;
      const int c32 = tid & 31;
      const float inv = 1.0f / srow[r];
      float* arow = attn_out + ((size_t)bh*4096 + row0 + r) * 4096;
      for (int iu = 0; iu < 16; ++iu) {
        int u = c32 + (iu << 5);
        int off = ((r << 13) + (u << 4)) ^ ((r & 7) << 4);
        s16x8 pv = *(s16x8*)(Plds + off);
        float4 o0, o1;
        o0.x = bf2f(pv[0])*inv; o0.y = bf2f(pv[1])*inv;
        o0.z = bf2f(pv[2])*inv; o0.w = bf2f(pv[3])*inv;
        o1.x = bf2f(pv[4])*inv; o1.y = bf2f(pv[5])*inv;
        o1.z = bf2f(pv[6])*inv; o1.w = bf2f(pv[7])*inv;
        *(float4*)(arow + (u << 3))     = o0;
        *(float4*)(arow + (u << 3) + 4) = o1;
      }
    }
    {
      f32x4 acc0 = {0.f,0.f,0.f,0.f};
      f32x4 acc1 = {0.f,0.f,0.f,0.f};
      const size_t vbase = (size_t)bh * (32*4096);
      for (int i2 = 0; i2 < 16; ++i2) {
        int kt = (wave << 4) + i2;
        int kk = (kt << 5) + lg*8;
        int aoff = ((l15 << 13) + (kk << 1)) ^ ((l15 & 7) << 4);
        s16x8 a  = *(s16x8*)(Plds + aoff);
        s16x8 b0 = *(const s16x8*)(vT16 + vbase + (size_t)l15*4096 + kk);
        s16x8 b1 = *(const s16x8*)(vT16 + vbase + (size_t)(16 + l15)*4096 + kk);
        acc0 = __builtin_amdgcn_mfma_f32_16x16x32_bf16(a, b0, acc0, 0, 0, 0);
        acc1 = __builtin_amdgcn_mfma_f32_16x16x32_bf16(a, b1, acc1, 0, 0, 0);
      }
      #pragma unroll
      for (int j = 0; j < 4; ++j) {
        int r = lg*4 + j;
        pvp[(wave << 9) + (r << 5) + l15]      = acc0[j];
        pvp[(wave << 9) + (r << 5) + 16 + l15] = acc1[j];
      }
    }
    __syncthreads();
    // reduce 8 wave-partials -> out_stage[b, n, h*32+d]
    {
      int r = tid >> 5, d = tid & 31;
      float acc = 0.f;
      #pragma unroll
      for (int w = 0; w < 8; ++w) acc += pvp[(w << 9) + tid];
      float res = acc / srow[r];
      int b = bh >> 2;
      out_stage[((size_t)(b*4096 + row0 + r))*128 + (h << 5) + d] = res;
    }
    __syncthreads();
  }
}

// ---------------- Kernel 3: output projection ----------------
__global__ __launch_bounds__(256)
void proj_kernel(const float* __restrict__ stage, const float* __restrict__ proj_w,
                 const float* __restrict__ proj_b, float* __restrict__ out)
{
  __shared__ float xs[16][129];
  const int tid = threadIdx.x;
  const int row0 = blockIdx.x * 16;
  for (int i = tid; i < 16*128; i += 256) {
    int r = i >> 7, c = i & 127;
    xs[r][c] = stage[(size_t)(row0 + r)*128 + c];
  }
  __syncthreads();
  for (int it = 0; it < 8; ++it) {
    int oc = tid & 127;
    int r  = (it << 1) + (tid >> 7);
    float acc = proj_b[oc];
    const float4* w4 = (const float4*)(proj_w + (size_t)oc*128);
    #pragma unroll 8
    for (int k4 = 0; k4 < 32; ++k4) {
      float4 wv = w4[k4];
      int k = k4 << 2;
      acc = fmaf(xs[r][k  ], wv.x, acc);
      acc = fmaf(xs[r][k+1], wv.y, acc);
      acc = fmaf(xs[r][k+2], wv.z, acc);
      acc = fmaf(xs[r][k+3], wv.w, acc);
    }
    out[(size_t)(row0 + r)*128 + oc] = acc;
  }
}

extern "C" void kernel_launch(void* const* d_in, const int* in_sizes, int n_in,
                              void* d_out, int out_size, void* d_ws, size_t ws_size,
                              hipStream_t stream) {
  const float* x          = (const float*)d_in[0];
  const float* q_w        = (const float*)d_in[1];
  const float* q_b        = (const float*)d_in[2];
  const float* kv_w       = (const float*)d_in[3];
  const float* kv_b       = (const float*)d_in[4];
  const float* proj_w     = (const float*)d_in[5];
  const float* proj_b     = (const float*)d_in[6];
  const float* bias_table = (const float*)d_in[7];
  // d_in[8] = rel_index (recomputed analytically), d_in[9]=H, d_in[10]=W (fixed 64)

  float* out  = (float*)d_out;                     // [2,4096,128]
  float* attn = (float*)d_out + 1048576;           // [2,4,4096,4096]

  char* ws = (char*)d_ws;                          // needs 10 MB
  short* q16   = (short*)(ws);                     // 2 MB  [8][4096][32] bf16
  short* k16   = (short*)(ws + (2u << 20));        // 2 MB
  short* vT16  = (short*)(ws + (4u << 20));        // 2 MB  [8][32][4096] bf16
  float* stage = (float*)(ws + (6u << 20));        // 4 MB  [2,4096,128] fp32

  qkv_kernel<<<dim3(512), dim3(256), 0, stream>>>(x, q_w, q_b, kv_w, kv_b, q16, k16, vT16);
  attn_kernel<<<dim3(256), dim3(512), 0, stream>>>(q16, k16, vT16, bias_table, attn, stage);
  proj_kernel<<<dim3(512), dim3(256), 0, stream>>>(stage, proj_w, proj_b, out);
}